// Round 8
// baseline (341.596 us; speedup 1.0000x reference)
//
#include <hip/hip_runtime.h>
#include <stdint.h>

// ---------- types ----------
typedef __attribute__((ext_vector_type(8))) __bf16 bf16x8;
typedef __attribute__((ext_vector_type(4))) float   f32x4;

__device__ __forceinline__ float bf2f(unsigned short u) {
    union { unsigned int i; float f; } v; v.i = ((unsigned int)u) << 16; return v.f;
}
__device__ __forceinline__ unsigned short f2bf(float f) {  // round-to-nearest-even
    unsigned int x = __builtin_bit_cast(unsigned int, f);
    x += 0x7FFFu + ((x >> 16) & 1u);
    return (unsigned short)(x >> 16);
}
__device__ __forceinline__ unsigned int pk2(float a, float b) {  // 2xbf16 packed
    return (unsigned int)f2bf(a) | ((unsigned int)f2bf(b) << 16);
}

// ---------- fused 3-weight cast (Wth 256x1024, Wph 256x1024, Wg 1024x1024) ----------
__global__ __launch_bounds__(256) void cast3_kernel(const float* __restrict__ a,
                                                    const float* __restrict__ b,
                                                    const float* __restrict__ c,
                                                    unsigned short* __restrict__ dA,
                                                    unsigned short* __restrict__ dB,
                                                    unsigned short* __restrict__ dC) {
    const int i = blockIdx.x * blockDim.x + threadIdx.x;   // 0..393215 (x4 elems)
    const float4* s4; ushort4* d4; int off;
    if (i < 65536)       { s4 = (const float4*)a; d4 = (ushort4*)dA; off = i; }
    else if (i < 131072) { s4 = (const float4*)b; d4 = (ushort4*)dB; off = i - 65536; }
    else                 { s4 = (const float4*)c; d4 = (ushort4*)dC; off = i - 131072; }
    float4 v = s4[off];
    ushort4 o;
    o.x = f2bf(v.x); o.y = f2bf(v.y); o.z = f2bf(v.z); o.w = f2bf(v.w);
    d4[off] = o;
}

// ---------- GEMM A (gemm0f): fused fp32->bf16 cast on the A path ----------
// C[M,NTOT] = cvt(X[M,K]) * W[NTOT,K]^T, fp32 X in, bf16 W in, fp32 accum,
// bias (split col 256), bf16 out. BM=128, BN=256, BK=64, 512 thr = 8 waves
// (2M x 4N), wave tile 64x64. A: reg-staged (load fp32, cvt, swizzled ds_write);
// B: global_load_lds. Counted vmcnt FIFO: per iter [A(t+2)x4, B(t+2)x4].
template<int NTOT, int NTI>
__global__ __launch_bounds__(512, 2)
void gemm0f(const float* __restrict__ X,
            const unsigned short* __restrict__ W,
            const float* __restrict__ bias0,
            const float* __restrict__ bias1,
            unsigned short* __restrict__ outb) {
    constexpr int K  = 1024;
    constexpr int NT = 16;                 // K-tiles of 64
    __shared__ unsigned short lds[49152];  // 2 x (A 128x64 + B 256x64) = 96 KB

    const int t    = threadIdx.x;
    const int wave = t >> 6;
    const int lane = t & 63;

    const int bid = blockIdx.x;
    const int xcd = bid & 7;               // HW round-robins blocks over 8 XCDs
    const int j   = bid >> 3;
    const int mt  = xcd * 48 + j / NTI;    // 384 M-tiles, 48 per XCD
    const int nt  = j % NTI;

    const int wr = wave >> 2;              // 0..1 : rows wr*64..
    const int wc = wave & 3;               // 0..3 : cols wc*64..

    // ---- A reg-staging geometry: thread t covers row t>>2, fp32 cols (t&3)*16..+16
    const int arow  = t >> 2;                          // 0..127
    const int acol0 = (t & 3) * 16;
    const float* gX = X + (size_t)(mt * 128 + arow) * K + acol0;
    const int s0e = ((t & 3) * 2)     ^ (arow & 7);    // swizzled 16B-chunk slots
    const int s1e = ((t & 3) * 2 + 1) ^ (arow & 7);

    // ---- B staging (global_load_lds, pre-swizzled source) ----
    const int srow = t >> 3;                           // 0..63
    const int scol = ((t & 7) ^ (srow & 7)) << 3;      // element offset
    const size_t bBase = (size_t)nt * 256 * K;
    const unsigned short* gB = W + bBase + (size_t)srow * K + scol;

    auto STAGE_B = [&](int tile) {                     // 4 gloads: rows 0..255
        unsigned short* lb = lds + (tile & 1) * 24576 + 8192;
        const unsigned short* gp = gB + tile * 64;
#pragma unroll
        for (int g = 0; g < 4; ++g)
            __builtin_amdgcn_global_load_lds(
                (const __attribute__((address_space(1))) void*)(gp + (size_t)(g * 64) * K),
                (__attribute__((address_space(3))) void*)(lb + g * 4096 + wave * 512), 16, 0, 0);
    };

    auto A_ISSUE = [&](int tile, float4 (&R)[4]) {
#pragma unroll
        for (int q = 0; q < 4; ++q)
            R[q] = *reinterpret_cast<const float4*>(gX + (size_t)tile * 64 + q * 4);
    };
    auto A_CONSUME = [&](int tile, const float4 (&R)[4]) {   // cvt + swizzled ds_write
        unsigned short* dst = lds + (tile & 1) * 24576 + arow * 64;
        uint4 u0, u1;
        u0.x = pk2(R[0].x, R[0].y); u0.y = pk2(R[0].z, R[0].w);
        u0.z = pk2(R[1].x, R[1].y); u0.w = pk2(R[1].z, R[1].w);
        u1.x = pk2(R[2].x, R[2].y); u1.y = pk2(R[2].z, R[2].w);
        u1.z = pk2(R[3].x, R[3].y); u1.w = pk2(R[3].z, R[3].w);
        *reinterpret_cast<uint4*>(dst + s0e * 8) = u0;
        *reinterpret_cast<uint4*>(dst + s1e * 8) = u1;
    };

    const int lr  = lane & 15;
    const int lkc = lane >> 4;
    auto LDA = [&](int buf, int mi, int kk) -> bf16x8 {
        const int row = wr * 64 + mi * 16 + lr;
        const int ch  = (kk * 4 + lkc) ^ (row & 7);
        return *reinterpret_cast<const bf16x8*>(&lds[buf * 24576 + row * 64 + ch * 8]);
    };
    auto LDB = [&](int buf, int ni, int kk) -> bf16x8 {
        const int row = wc * 64 + ni * 16 + lr;
        const int ch  = (kk * 4 + lkc) ^ (row & 7);
        return *reinterpret_cast<const bf16x8*>(&lds[buf * 24576 + 8192 + row * 64 + ch * 8]);
    };

    f32x4 acc[4][4];
#pragma unroll
    for (int m = 0; m < 4; ++m)
#pragma unroll
        for (int n = 0; n < 4; ++n) acc[m][n] = f32x4{0.f, 0.f, 0.f, 0.f};

    float4 rA[4], rB[4];   // A fp32 regs: even tiles in rA, odd in rB

    // prologue FIFO: A0(4), B0(4), A1(4), B1(4)
    A_ISSUE(0, rA); STAGE_B(0);
    A_ISSUE(1, rB); STAGE_B(1);
    asm volatile("s_waitcnt vmcnt(12)" ::: "memory");   // A0 regs ready
    A_CONSUME(0, rA);
    asm volatile("s_waitcnt vmcnt(8)" ::: "memory");    // B0 landed (A1,B1 in flight)
    asm volatile("s_waitcnt lgkmcnt(0)" ::: "memory");  // A0 ds_writes retired
    __builtin_amdgcn_s_barrier();
    asm volatile("" ::: "memory");

    bf16x8 af[4][2], b0[2][2], b1[2][2];

    // iteration body: consume A(tt+1) from RC, load A(tt+2) into RL
#define ITER(tt, RC, RL)                                                          \
    {                                                                             \
        const int buf = (tt) & 1;                                                 \
        /* ph0: frag reads Q0; A pipeline; barrier; MFMA Q0 */                    \
        _Pragma("unroll")                                                         \
        for (int m = 0; m < 4; ++m) { af[m][0] = LDA(buf, m, 0); af[m][1] = LDA(buf, m, 1); } \
        _Pragma("unroll")                                                         \
        for (int n = 0; n < 2; ++n) { b0[n][0] = LDB(buf, n, 0); b0[n][1] = LDB(buf, n, 1); } \
        if ((tt) < NT - 2) {                                                      \
            A_ISSUE((tt) + 2, RL);                                                \
            asm volatile("s_waitcnt vmcnt(8)" ::: "memory");                      \
            A_CONSUME((tt) + 1, RC);                                              \
        } else if ((tt) == NT - 2) {                                              \
            asm volatile("s_waitcnt vmcnt(4)" ::: "memory");                      \
            A_CONSUME((tt) + 1, RC);                                              \
        }                                                                         \
        asm volatile("" ::: "memory");                                            \
        __builtin_amdgcn_s_barrier();                                             \
        if ((tt) < NT - 1) asm volatile("s_waitcnt lgkmcnt(2)" ::: "memory");     \
        else               asm volatile("s_waitcnt lgkmcnt(0)" ::: "memory");     \
        __builtin_amdgcn_sched_barrier(0);                                        \
        __builtin_amdgcn_s_setprio(1);                                            \
        _Pragma("unroll")                                                         \
        for (int m = 0; m < 4; ++m)                                               \
            _Pragma("unroll")                                                     \
            for (int n = 0; n < 2; ++n)                                           \
                _Pragma("unroll")                                                 \
                for (int kk = 0; kk < 2; ++kk)                                    \
                    acc[m][n] = __builtin_amdgcn_mfma_f32_16x16x32_bf16(af[m][kk], b0[n][kk], acc[m][n], 0, 0, 0); \
        __builtin_amdgcn_s_setprio(0);                                            \
        asm volatile("" ::: "memory");                                            \
        __builtin_amdgcn_s_barrier();                                             \
        asm volatile("" ::: "memory");                                            \
        /* ph1: frag reads Q1; barrier; MFMA Q1; stage B(t+2); gate */            \
        _Pragma("unroll")                                                         \
        for (int n = 0; n < 2; ++n) { b1[n][0] = LDB(buf, 2 + n, 0); b1[n][1] = LDB(buf, 2 + n, 1); } \
        asm volatile("" ::: "memory");                                            \
        __builtin_amdgcn_s_barrier();                                             \
        asm volatile("s_waitcnt lgkmcnt(0)" ::: "memory");                        \
        __builtin_amdgcn_sched_barrier(0);                                        \
        __builtin_amdgcn_s_setprio(1);                                            \
        _Pragma("unroll")                                                         \
        for (int m = 0; m < 4; ++m)                                               \
            _Pragma("unroll")                                                     \
            for (int n = 0; n < 2; ++n)                                           \
                _Pragma("unroll")                                                 \
                for (int kk = 0; kk < 2; ++kk)                                    \
                    acc[m][2 + n] = __builtin_amdgcn_mfma_f32_16x16x32_bf16(af[m][kk], b1[n][kk], acc[m][2 + n], 0, 0, 0); \
        __builtin_amdgcn_s_setprio(0);                                            \
        __builtin_amdgcn_sched_barrier(0);                                        \
        if ((tt) + 2 < NT) STAGE_B((tt) + 2);                                     \
        if ((tt) < NT - 2)       asm volatile("s_waitcnt vmcnt(8)" ::: "memory"); \
        else if ((tt) == NT - 2) asm volatile("s_waitcnt vmcnt(0)" ::: "memory"); \
        asm volatile("" ::: "memory");                                            \
        __builtin_amdgcn_s_barrier();                                             \
        asm volatile("" ::: "memory");                                            \
    }

    for (int tp = 0; tp < NT / 2; ++tp) {
        ITER(2 * tp,     rB, rA);   // consumes A(odd) from rB, loads A(even) into rA
        ITER(2 * tp + 1, rA, rB);   // consumes A(even) from rA, loads A(odd) into rB
    }
#undef ITER

    // -------- epilogue: acc -> LDS (single pass, 72 KB) -> coalesced bf16 stores --------
    const int rowOff = (lane >> 4) * 4;   // C/D: col = lane&15, row = rowOff + r
    unsigned short* lu = lds;             // 8 regions x 64 x 72 shorts
#pragma unroll
    for (int mq = 0; mq < 4; ++mq)
#pragma unroll
        for (int n = 0; n < 4; ++n) {
            const int gc = nt * 256 + wc * 64 + n * 16 + lr;
            const float bv = (gc < 256) ? bias0[gc] : bias1[gc - 256];
#pragma unroll
            for (int r = 0; r < 4; ++r)
                lu[wave * 4608 + (mq * 16 + rowOff + r) * 72 + n * 16 + lr] =
                    f2bf(acc[mq][n][r] + bv);
        }
    __syncthreads();
#pragma unroll
    for (int it = 0; it < 8; ++it) {      // 128 rows x 256 cols bf16
        const int flat = it * 4096 + t * 8;   // shorts
        const int row  = flat >> 8;           // 0..127
        const int col  = flat & 255;
        const int wv   = (row >> 6) * 4 + (col >> 6);
        uint4 v = *reinterpret_cast<const uint4*>(&lu[wv * 4608 + (row & 63) * 72 + (col & 63)]);
        *reinterpret_cast<uint4*>(outb + (size_t)(mt * 128 + row) * NTOT + nt * 256 + col) = v;
    }
}

// ---------- GEMM B: 256x256 tile (gemm1, round-4 variant, relu + fp32 out) ----------
template<int NTOT, int NTI>
__global__ __launch_bounds__(512, 2)
void gemm_bt(const unsigned short* __restrict__ A,
             const unsigned short* __restrict__ W,
             float* __restrict__ outf) {
    constexpr int K  = 1024;
    constexpr int NT = 16;                 // K-tiles of 64
    __shared__ unsigned short lds[65536];  // 2 x (A 256x64 + B 256x64) = 128 KB

    const int t    = threadIdx.x;
    const int wave = t >> 6;
    const int lane = t & 63;

    const int bid = blockIdx.x;
    const int xcd = bid & 7;
    const int j   = bid >> 3;
    const int mt  = xcd * 24 + j / NTI;    // 192 M-tiles, 24 per XCD
    const int nt  = j % NTI;

    const int wr = wave >> 2;              // 0..1 : M half (rows wr*128..)
    const int wc = wave & 3;               // 0..3 : N quarter (cols wc*64..)

    const size_t aBase = (size_t)mt * 256 * K;
    const size_t bBase = (size_t)nt * 256 * K;

    const int srow = t >> 3;                          // 0..63
    const int scol = ((t & 7) ^ (srow & 7)) << 3;     // element offset
    const unsigned short* gA = A + aBase + (size_t)srow * K + scol;
    const unsigned short* gB = W + bBase + (size_t)srow * K + scol;

    auto STAGE = [&](int tile, int isB, int half) {
        unsigned short* lb = lds + (tile & 1) * 32768 + isB * 16384 + half * 8192;
        const unsigned short* gp = (isB ? gB : gA) + (size_t)(half * 128) * K + tile * 64;
#pragma unroll
        for (int g = 0; g < 2; ++g)
            __builtin_amdgcn_global_load_lds(
                (const __attribute__((address_space(1))) void*)(gp + (size_t)(g * 64) * K),
                (__attribute__((address_space(3))) void*)(lb + g * 4096 + wave * 512), 16, 0, 0);
    };

    const int lr  = lane & 15;
    const int lkc = lane >> 4;
    auto LDA = [&](int buf, int mi, int kk) -> bf16x8 {
        const int row = wr * 128 + mi * 16 + lr;
        const int ch  = (kk * 4 + lkc) ^ (row & 7);
        return *reinterpret_cast<const bf16x8*>(&lds[buf * 32768 + row * 64 + ch * 8]);
    };
    auto LDB = [&](int buf, int ni, int kk) -> bf16x8 {
        const int row = wc * 64 + ni * 16 + lr;
        const int ch  = (kk * 4 + lkc) ^ (row & 7);
        return *reinterpret_cast<const bf16x8*>(&lds[buf * 32768 + 16384 + row * 64 + ch * 8]);
    };

    f32x4 acc[8][4];
#pragma unroll
    for (int m = 0; m < 8; ++m)
#pragma unroll
        for (int n = 0; n < 4; ++n) acc[m][n] = f32x4{0.f, 0.f, 0.f, 0.f};

    // prologue: B(0), A(0), B(1)
    STAGE(0, 1, 0); STAGE(0, 1, 1);
    STAGE(0, 0, 0); STAGE(0, 0, 1);
    STAGE(1, 1, 0); STAGE(1, 1, 1);
    asm volatile("s_waitcnt vmcnt(4)" ::: "memory");
    __builtin_amdgcn_s_barrier();
    asm volatile("" ::: "memory");

    bf16x8 af[4][2], bfr[4][2];

#define MID_BARRIER()                                      \
    asm volatile("" ::: "memory");                         \
    __builtin_amdgcn_s_barrier();                          \
    asm volatile("s_waitcnt lgkmcnt(0)" ::: "memory");     \
    __builtin_amdgcn_sched_barrier(0);

#define END_BARRIER()                                      \
    asm volatile("" ::: "memory");                         \
    __builtin_amdgcn_s_barrier();                          \
    asm volatile("" ::: "memory");

    for (int tt = 0; tt < NT; ++tt) {
        const int buf = tt & 1;

        // ph0: reads A m0-3 + B n0-1; stage A-h0(tt+1); MFMA Q0
#pragma unroll
        for (int m = 0; m < 4; ++m) { af[m][0] = LDA(buf, m, 0); af[m][1] = LDA(buf, m, 1); }
#pragma unroll
        for (int n = 0; n < 2; ++n) { bfr[n][0] = LDB(buf, n, 0); bfr[n][1] = LDB(buf, n, 1); }
        if (tt + 1 < NT) STAGE(tt + 1, 0, 0);
        MID_BARRIER();
        __builtin_amdgcn_s_setprio(1);
#pragma unroll
        for (int m = 0; m < 4; ++m)
#pragma unroll
            for (int n = 0; n < 2; ++n)
#pragma unroll
                for (int kk = 0; kk < 2; ++kk)
                    acc[m][n] = __builtin_amdgcn_mfma_f32_16x16x32_bf16(af[m][kk], bfr[n][kk], acc[m][n], 0, 0, 0);
        __builtin_amdgcn_s_setprio(0);
        END_BARRIER();

        // ph1: reads B n2-3; stage A-h1(tt+1); MFMA Q1
#pragma unroll
        for (int n = 0; n < 2; ++n) { bfr[2 + n][0] = LDB(buf, 2 + n, 0); bfr[2 + n][1] = LDB(buf, 2 + n, 1); }
        if (tt + 1 < NT) STAGE(tt + 1, 0, 1);
        MID_BARRIER();
        __builtin_amdgcn_s_setprio(1);
#pragma unroll
        for (int m = 0; m < 4; ++m)
#pragma unroll
            for (int n = 0; n < 2; ++n)
#pragma unroll
                for (int kk = 0; kk < 2; ++kk)
                    acc[m][2 + n] = __builtin_amdgcn_mfma_f32_16x16x32_bf16(af[m][kk], bfr[2 + n][kk], acc[m][2 + n], 0, 0, 0);
        __builtin_amdgcn_s_setprio(0);
        END_BARRIER();

        // ph2: reads A m4-7; stage B-h0(tt+2); MFMA Q2
#pragma unroll
        for (int m = 0; m < 4; ++m) { af[m][0] = LDA(buf, 4 + m, 0); af[m][1] = LDA(buf, 4 + m, 1); }
        if (tt + 2 < NT) STAGE(tt + 2, 1, 0);
        MID_BARRIER();
        __builtin_amdgcn_s_setprio(1);
#pragma unroll
        for (int m = 0; m < 4; ++m)
#pragma unroll
            for (int n = 0; n < 2; ++n)
#pragma unroll
                for (int kk = 0; kk < 2; ++kk)
                    acc[4 + m][n] = __builtin_amdgcn_mfma_f32_16x16x32_bf16(af[m][kk], bfr[n][kk], acc[4 + m][n], 0, 0, 0);
        __builtin_amdgcn_s_setprio(0);
        END_BARRIER();

        // ph3: stage B-h1(tt+2); MFMA Q3; vmcnt gate
        if (tt + 2 < NT) STAGE(tt + 2, 1, 1);
        asm volatile("" ::: "memory");
        __builtin_amdgcn_s_barrier();
        __builtin_amdgcn_sched_barrier(0);
        __builtin_amdgcn_s_setprio(1);
#pragma unroll
        for (int m = 0; m < 4; ++m)
#pragma unroll
            for (int n = 0; n < 2; ++n)
#pragma unroll
                for (int kk = 0; kk < 2; ++kk)
                    acc[4 + m][2 + n] = __builtin_amdgcn_mfma_f32_16x16x32_bf16(af[m][kk], bfr[2 + n][kk], acc[4 + m][2 + n], 0, 0, 0);
        __builtin_amdgcn_s_setprio(0);
        if (tt < NT - 2)       asm volatile("s_waitcnt vmcnt(4)" ::: "memory");
        else if (tt == NT - 2) asm volatile("s_waitcnt vmcnt(0)" ::: "memory");
        END_BARRIER();
    }
#undef MID_BARRIER
#undef END_BARRIER

    // epilogue: relu, fp32 direct
    const int rowOff = (lane >> 4) * 4;
#pragma unroll
    for (int m = 0; m < 8; ++m)
#pragma unroll
        for (int n = 0; n < 4; ++n)
#pragma unroll
            for (int r = 0; r < 4; ++r)
                outf[(size_t)(mt * 256 + wr * 128 + m * 16 + rowOff + r) * NTOT
                     + nt * 256 + wc * 64 + n * 16 + lr] = fmaxf(acc[m][n][r], 0.f);
}

// ---------- per-batch: sim -> mask -> softmax -> relation + agg ----------
__global__ __launch_bounds__(256)
void relation_kernel(const unsigned short* __restrict__ TP,   // [M,512] bf16: theta|phi
                     const float* __restrict__ boxes,         // [M,4]
                     const float* __restrict__ X,             // [M,1024] fp32
                     unsigned short* __restrict__ aggb,       // [M,1024] bf16 out
                     float* __restrict__ relout) {            // [BT,12,12] fp32
    __shared__ float th[12][260];
    __shared__ float ph[12][260];
    __shared__ unsigned short xls[12 * 1024];
    __shared__ float cx[12], cy[12];
    __shared__ float sim[12][12];
    __shared__ float rel[12][12];

    const int b = blockIdx.x;
    const int t = threadIdx.x;

    if (t < 12) {
        const float* bx = boxes + ((size_t)b * 12 + t) * 4;
        cx[t] = (bx[0] + bx[2]) * 0.5f;
        cy[t] = (bx[1] + bx[3]) * 0.5f;
    }
    const uint4* tp4 = (const uint4*)(TP + (size_t)b * 6144);
    for (int c = t; c < 768; c += 256) {
        uint4 v = tp4[c];
        const unsigned short* pv = (const unsigned short*)&v;
        const int n = c >> 6;
        const int c0 = (c & 63) << 3;
        if (c0 < 256) {
#pragma unroll
            for (int jj = 0; jj < 8; ++jj) th[n][c0 + jj] = bf2f(pv[jj]);
        } else {
#pragma unroll
            for (int jj = 0; jj < 8; ++jj) ph[n][c0 - 256 + jj] = bf2f(pv[jj]);
        }
    }
    // stage x tile from fp32, convert to bf16 (bit-identical to previous cast path)
    const float4* x4 = (const float4*)(X + (size_t)b * 12288);
    for (int c = t; c < 3072; c += 256) {
        float4 v = x4[c];
        ushort4 o;
        o.x = f2bf(v.x); o.y = f2bf(v.y); o.z = f2bf(v.z); o.w = f2bf(v.w);
        *reinterpret_cast<ushort4*>(&xls[c * 4]) = o;
    }
    __syncthreads();

    if (t < 144) {
        const int n = t / 12, m = t - (t / 12) * 12;
        float a = 0.f;
#pragma unroll 8
        for (int r = 0; r < 256; ++r) a += th[n][r] * ph[m][r];
        const float dx = cx[n] - cx[m], dy = cy[n] - cy[m];
        const float d2 = dx * dx + dy * dy;
        const float thr = 31.4f;  // POS_THRESHOLD * OW
        sim[n][m] = (d2 > thr * thr) ? -__builtin_inff() : a * 0.0625f;
    }
    __syncthreads();

    if (t < 12) {
        float mx = -__builtin_inff();
#pragma unroll
        for (int m = 0; m < 12; ++m) mx = fmaxf(mx, sim[t][m]);
        float e[12]; float s = 0.f;
#pragma unroll
        for (int m = 0; m < 12; ++m) { e[m] = expf(sim[t][m] - mx); s += e[m]; }
        const float inv = 1.f / s;
#pragma unroll
        for (int m = 0; m < 12; ++m) {
            const float r = e[m] * inv;
            rel[t][m] = r;
            relout[(size_t)b * 144 + t * 12 + m] = r;
        }
    }
    __syncthreads();

    unsigned short* aggp = aggb + (size_t)b * 12288;
    for (int f = t; f < 1024; f += 256) {
        float xv[12];
#pragma unroll
        for (int m = 0; m < 12; ++m) xv[m] = bf2f(xls[m * 1024 + f]);
#pragma unroll
        for (int n = 0; n < 12; ++n) {
            float a = 0.f;
#pragma unroll
            for (int m = 0; m < 12; ++m) a += rel[n][m] * xv[m];
            aggp[n * 1024 + f] = f2bf(a);
        }
    }
}

// ---------- launcher ----------
extern "C" void kernel_launch(void* const* d_in, const int* in_sizes, int n_in,
                              void* d_out, int out_size, void* d_ws, size_t ws_size,
                              hipStream_t stream) {
    const float* x     = (const float*)d_in[0];  // [4096,12,1024] fp32
    const float* boxes = (const float*)d_in[1];  // [49152,4]
    const float* Wth   = (const float*)d_in[2];  // [256,1024]
    const float* bth   = (const float*)d_in[3];  // [256]
    const float* Wph   = (const float*)d_in[4];  // [256,1024]
    const float* bph   = (const float*)d_in[5];  // [256]
    const float* Wg    = (const float*)d_in[6];  // [1024,1024]
    float* out = (float*)d_out;                  // 49152*1024 out | 4096*144 relation

    const int M = 49152;
    const size_t XE = (size_t)M * 1024;

    char* ws = (char*)d_ws;
    unsigned short* aggb = (unsigned short*)ws;                 // [M,1024] bf16 agg
    unsigned short* TP   = (unsigned short*)(ws + 100663296);   // [M,512] bf16 theta|phi
    unsigned short* Wcat = (unsigned short*)(ws + 150994944);   // [512,1024] bf16
    unsigned short* Wgb  = (unsigned short*)(ws + 152043520);   // [1024,1024] bf16

    cast3_kernel<<<1536, 256, 0, stream>>>(Wth, Wph, Wg, Wcat, Wcat + 262144, Wgb);

    // gemm0f: fused cast, 384 M-tiles (48/XCD) x NTI=2 -> 768 blocks
    gemm0f<512, 2><<<dim3(768), 512, 0, stream>>>(x, Wcat, bth, bph, TP);

    relation_kernel<<<4096, 256, 0, stream>>>(TP, boxes, x, aggb, out + XE);

    // gemm1: 192 M-tiles (24/XCD) x NTI=4 -> 768 blocks
    gemm_bt<1024, 4><<<dim3(768), 512, 0, stream>>>(aggb, Wgb, out);
}

// Round 9
// 317.792 us; speedup vs baseline: 1.0749x; 1.0749x over previous
//
#include <hip/hip_runtime.h>
#include <stdint.h>

// ---------- types ----------
typedef __attribute__((ext_vector_type(8))) __bf16 bf16x8;
typedef __attribute__((ext_vector_type(8))) float   f32x8;
typedef __attribute__((ext_vector_type(4))) float   f32x4;

__device__ __forceinline__ float bf2f(unsigned short u) {
    union { unsigned int i; float f; } v; v.i = ((unsigned int)u) << 16; return v.f;
}
__device__ __forceinline__ unsigned short f2bf(float f) {  // round-to-nearest-even
    unsigned int x = __builtin_bit_cast(unsigned int, f);
    x += 0x7FFFu + ((x >> 16) & 1u);
    return (unsigned short)(x >> 16);
}

// ---------- fused 3-weight cast (Wth 256x1024, Wph 256x1024, Wg 1024x1024) ----------
__global__ __launch_bounds__(256) void cast3_kernel(const float* __restrict__ a,
                                                    const float* __restrict__ b,
                                                    const float* __restrict__ c,
                                                    unsigned short* __restrict__ dA,
                                                    unsigned short* __restrict__ dB,
                                                    unsigned short* __restrict__ dC) {
    const int i = blockIdx.x * blockDim.x + threadIdx.x;   // 0..393215 (x4 elems)
    const float4* s4; ushort4* d4; int off;
    if (i < 65536)       { s4 = (const float4*)a; d4 = (ushort4*)dA; off = i; }
    else if (i < 131072) { s4 = (const float4*)b; d4 = (ushort4*)dB; off = i - 65536; }
    else                 { s4 = (const float4*)c; d4 = (ushort4*)dC; off = i - 131072; }
    float4 v = s4[off];
    ushort4 o;
    o.x = f2bf(v.x); o.y = f2bf(v.y); o.z = f2bf(v.z); o.w = f2bf(v.w);
    d4[off] = o;
}

// ---------- GEMM A (gemm0h): fp32 A staged via global_load_lds, cvt at frag read ----------
// C[M,512] = cvt(X[M,K]) * W[512,K]^T, fp32 X in, bf16 W in, fp32 accum,
// bias (split col 256), bf16 out. BM=128, BN=256, BK=64, 512 thr = 8 waves
// (2M x 4N), wave tile 64x64. Round-7 gemm_bt128 schedule verbatim; only the
// A staging width (fp32) and A frag-read path (ds_read x2 + convertvector) change.
// A LDS: 128 rows x 256B (16 chunks of 16B), slot = chunk ^ (row & 15)
//   (read key = lr -> 16 distinct slots -> 2 lanes/bank = free).
template<int NTOT, int NTI>
__global__ __launch_bounds__(512, 2)
void gemm0h(const float* __restrict__ X,
            const unsigned short* __restrict__ W,
            const float* __restrict__ bias0,
            const float* __restrict__ bias1,
            unsigned short* __restrict__ outb) {
    constexpr int K  = 1024;
    constexpr int NT = 16;                  // K-tiles of 64
    __shared__ unsigned char lds[131072];   // 2 x (A 32KB fp32 + B 32KB bf16)

    const int t    = threadIdx.x;
    const int wave = t >> 6;
    const int lane = t & 63;

    const int bid = blockIdx.x;
    const int xcd = bid & 7;                // HW round-robins blocks over 8 XCDs
    const int j   = bid >> 3;
    const int mt  = xcd * 48 + j / NTI;     // 384 M-tiles, 48 per XCD
    const int nt  = j % NTI;

    const int wr = wave >> 2;               // 0..1 : rows wr*64..
    const int wc = wave & 3;                // 0..3 : cols wc*64..

    // ---- A staging: 4 instrs/tile, thread t covers row t>>4 (of 32-row group),
    //      global chunk (t&15) ^ ((t>>4)&15)  [pre-swizzled source, key=row&15]
    const int arow   = t >> 4;                         // 0..31 within group
    const int achunk = (t & 15) ^ (arow & 15);         // global 16B-chunk (4 floats)
    const float* gXs = X + (size_t)(mt * 128 + arow) * K + achunk * 4;

    auto STAGE_A = [&](int tile) {
        unsigned char* lb = lds + (tile & 1) * 65536;
#pragma unroll
        for (int i = 0; i < 4; ++i)
            __builtin_amdgcn_global_load_lds(
                (const __attribute__((address_space(1))) void*)(gXs + (size_t)(i * 32) * K + tile * 64),
                (__attribute__((address_space(3))) void*)(lb + i * 8192 + wave * 1024), 16, 0, 0);
    };

    // ---- B staging (bf16, 3-bit chunk-XOR, as validated) ----
    const int srow = t >> 3;                           // 0..63
    const int scol = ((t & 7) ^ (srow & 7)) << 3;      // element offset
    const unsigned short* gB = W + (size_t)nt * 256 * K + (size_t)srow * K + scol;

    auto STAGE_B = [&](int tile) {                     // 4 gloads: rows 0..255
        unsigned char* lb = lds + (tile & 1) * 65536 + 32768;
        const unsigned short* gp = gB + tile * 64;
#pragma unroll
        for (int g = 0; g < 4; ++g)
            __builtin_amdgcn_global_load_lds(
                (const __attribute__((address_space(1))) void*)(gp + (size_t)(g * 64) * K),
                (__attribute__((address_space(3))) void*)(lb + g * 8192 + wave * 1024), 16, 0, 0);
    };

    const int lr  = lane & 15;
    const int lkc = lane >> 4;
    // A frag: row = wr*64 + mi*16 + lr; key = row&15 = lr; chunks c0, c0+1 (c0 even)
    const int aRowByte = (wr * 64 + lr) * 256;         // + mi*4096
    int aLo[2], aHi[2];
#pragma unroll
    for (int kk = 0; kk < 2; ++kk) {
        const int c0 = kk * 8 + lkc * 2;
        aLo[kk] = ((c0     ) ^ lr) * 16;
        aHi[kk] = ((c0 + 1 ) ^ lr) * 16;
    }
    auto LDA = [&](int bufB, int mi, int kk) -> bf16x8 {
        const unsigned char* base = lds + bufB + aRowByte + mi * 4096;
        f32x4 lo = *reinterpret_cast<const f32x4*>(base + aLo[kk]);
        f32x4 hi = *reinterpret_cast<const f32x4*>(base + aHi[kk]);
        f32x8 f; f.lo = lo; f.hi = hi;
        return __builtin_convertvector(f, bf16x8);     // RNE, matches f2bf
    };
    // B frag: row = wc*64 + ni*16 + lr; key = lr&7
    const int bRowByte = 32768 + (wc * 64 + lr) * 128; // + ni*2048
    int bOff[2];
#pragma unroll
    for (int kk = 0; kk < 2; ++kk)
        bOff[kk] = (((kk * 4 + lkc) ^ (lr & 7)) * 16);
    auto LDB = [&](int bufB, int ni, int kk) -> bf16x8 {
        return *reinterpret_cast<const bf16x8*>(lds + bufB + bRowByte + ni * 2048 + bOff[kk]);
    };

    f32x4 acc[4][4];
#pragma unroll
    for (int m = 0; m < 4; ++m)
#pragma unroll
        for (int n = 0; n < 4; ++n) acc[m][n] = f32x4{0.f, 0.f, 0.f, 0.f};

    // prologue FIFO: A0(4), B0(4), B1(4) -> wait-to-4 lands tile 0, B1 in flight
    STAGE_A(0); STAGE_B(0); STAGE_B(1);
    asm volatile("s_waitcnt vmcnt(4)" ::: "memory");
    __builtin_amdgcn_s_barrier();
    asm volatile("" ::: "memory");

    bf16x8 af[4][2], b0[2][2], b1[2][2];

    for (int tt = 0; tt < NT; ++tt) {
        const int bufB = (tt & 1) * 65536;

        // ---- ph0: frag reads A m0-3 + B n0-1; stage A(t+1) (buf^1, safe); MFMA Q0 ----
#pragma unroll
        for (int m = 0; m < 4; ++m) { af[m][0] = LDA(bufB, m, 0); af[m][1] = LDA(bufB, m, 1); }
#pragma unroll
        for (int n = 0; n < 2; ++n) { b0[n][0] = LDB(bufB, n, 0); b0[n][1] = LDB(bufB, n, 1); }
        if (tt + 1 < NT) STAGE_A(tt + 1);
        asm volatile("" ::: "memory");
        __builtin_amdgcn_s_barrier();
        asm volatile("s_waitcnt lgkmcnt(0)" ::: "memory");
        __builtin_amdgcn_sched_barrier(0);
        __builtin_amdgcn_s_setprio(1);
#pragma unroll
        for (int m = 0; m < 4; ++m)
#pragma unroll
            for (int n = 0; n < 2; ++n)
#pragma unroll
                for (int kk = 0; kk < 2; ++kk)
                    acc[m][n] = __builtin_amdgcn_mfma_f32_16x16x32_bf16(af[m][kk], b0[n][kk], acc[m][n], 0, 0, 0);
        __builtin_amdgcn_s_setprio(0);
        asm volatile("" ::: "memory");
        __builtin_amdgcn_s_barrier();
        asm volatile("" ::: "memory");

        // ---- ph1: frag reads B n2-3; MFMA Q1; stage B(t+2); counted gate ----
#pragma unroll
        for (int n = 0; n < 2; ++n) { b1[n][0] = LDB(bufB, 2 + n, 0); b1[n][1] = LDB(bufB, 2 + n, 1); }
        asm volatile("" ::: "memory");
        __builtin_amdgcn_s_barrier();
        asm volatile("s_waitcnt lgkmcnt(0)" ::: "memory");
        __builtin_amdgcn_sched_barrier(0);
        __builtin_amdgcn_s_setprio(1);
#pragma unroll
        for (int m = 0; m < 4; ++m)
#pragma unroll
            for (int n = 0; n < 2; ++n)
#pragma unroll
                for (int kk = 0; kk < 2; ++kk)
                    acc[m][2 + n] = __builtin_amdgcn_mfma_f32_16x16x32_bf16(af[m][kk], b1[n][kk], acc[m][2 + n], 0, 0, 0);
        __builtin_amdgcn_s_setprio(0);
        __builtin_amdgcn_sched_barrier(0);
        if (tt + 2 < NT) STAGE_B(tt + 2);
        // gate FIFO: [B(t+1)x4, A(t+1)x4, B(t+2)x4] -> wait-to-4 = tile t+1 landed
        if (tt < NT - 2)       asm volatile("s_waitcnt vmcnt(4)" ::: "memory");
        else if (tt == NT - 2) asm volatile("s_waitcnt vmcnt(0)" ::: "memory");
        asm volatile("" ::: "memory");
        __builtin_amdgcn_s_barrier();
        asm volatile("" ::: "memory");
    }

    // -------- epilogue: acc -> LDS (single pass, 72 KB) -> coalesced bf16 stores --------
    const int rowOff = (lane >> 4) * 4;   // C/D: col = lane&15, row = rowOff + r
    unsigned short* lu = (unsigned short*)lds;   // 8 regions x 64 x 72 shorts
#pragma unroll
    for (int mq = 0; mq < 4; ++mq)
#pragma unroll
        for (int n = 0; n < 4; ++n) {
            const int gc = nt * 256 + wc * 64 + n * 16 + lr;
            const float bv = (gc < 256) ? bias0[gc] : bias1[gc - 256];
#pragma unroll
            for (int r = 0; r < 4; ++r)
                lu[wave * 4608 + (mq * 16 + rowOff + r) * 72 + n * 16 + lr] =
                    f2bf(acc[mq][n][r] + bv);
        }
    __syncthreads();
#pragma unroll
    for (int it = 0; it < 8; ++it) {      // 128 rows x 256 cols bf16
        const int flat = it * 4096 + t * 8;   // shorts
        const int row  = flat >> 8;           // 0..127
        const int col  = flat & 255;
        const int wv   = (row >> 6) * 4 + (col >> 6);
        uint4 v = *reinterpret_cast<const uint4*>(&lu[wv * 4608 + (row & 63) * 72 + (col & 63)]);
        *reinterpret_cast<uint4*>(outb + (size_t)(mt * 128 + row) * NTOT + nt * 256 + col) = v;
    }
}

// ---------- GEMM B: 256x256 tile (gemm1, round-4/7 variant, relu + fp32 out) ----------
template<int NTOT, int NTI>
__global__ __launch_bounds__(512, 2)
void gemm_bt(const unsigned short* __restrict__ A,
             const unsigned short* __restrict__ W,
             float* __restrict__ outf) {
    constexpr int K  = 1024;
    constexpr int NT = 16;                 // K-tiles of 64
    __shared__ unsigned short lds[65536];  // 2 x (A 256x64 + B 256x64) = 128 KB

    const int t    = threadIdx.x;
    const int wave = t >> 6;
    const int lane = t & 63;

    const int bid = blockIdx.x;
    const int xcd = bid & 7;
    const int j   = bid >> 3;
    const int mt  = xcd * 24 + j / NTI;    // 192 M-tiles, 24 per XCD
    const int nt  = j % NTI;

    const int wr = wave >> 2;              // 0..1 : M half (rows wr*128..)
    const int wc = wave & 3;               // 0..3 : N quarter (cols wc*64..)

    const size_t aBase = (size_t)mt * 256 * K;
    const size_t bBase = (size_t)nt * 256 * K;

    const int srow = t >> 3;                          // 0..63
    const int scol = ((t & 7) ^ (srow & 7)) << 3;     // element offset
    const unsigned short* gA = A + aBase + (size_t)srow * K + scol;
    const unsigned short* gB = W + bBase + (size_t)srow * K + scol;

    auto STAGE = [&](int tile, int isB, int half) {
        unsigned short* lb = lds + (tile & 1) * 32768 + isB * 16384 + half * 8192;
        const unsigned short* gp = (isB ? gB : gA) + (size_t)(half * 128) * K + tile * 64;
#pragma unroll
        for (int g = 0; g < 2; ++g)
            __builtin_amdgcn_global_load_lds(
                (const __attribute__((address_space(1))) void*)(gp + (size_t)(g * 64) * K),
                (__attribute__((address_space(3))) void*)(lb + g * 4096 + wave * 512), 16, 0, 0);
    };

    const int lr  = lane & 15;
    const int lkc = lane >> 4;
    auto LDA = [&](int buf, int mi, int kk) -> bf16x8 {
        const int row = wr * 128 + mi * 16 + lr;
        const int ch  = (kk * 4 + lkc) ^ (row & 7);
        return *reinterpret_cast<const bf16x8*>(&lds[buf * 32768 + row * 64 + ch * 8]);
    };
    auto LDB = [&](int buf, int ni, int kk) -> bf16x8 {
        const int row = wc * 64 + ni * 16 + lr;
        const int ch  = (kk * 4 + lkc) ^ (row & 7);
        return *reinterpret_cast<const bf16x8*>(&lds[buf * 32768 + 16384 + row * 64 + ch * 8]);
    };

    f32x4 acc[8][4];
#pragma unroll
    for (int m = 0; m < 8; ++m)
#pragma unroll
        for (int n = 0; n < 4; ++n) acc[m][n] = f32x4{0.f, 0.f, 0.f, 0.f};

    // prologue: B(0), A(0), B(1)
    STAGE(0, 1, 0); STAGE(0, 1, 1);
    STAGE(0, 0, 0); STAGE(0, 0, 1);
    STAGE(1, 1, 0); STAGE(1, 1, 1);
    asm volatile("s_waitcnt vmcnt(4)" ::: "memory");
    __builtin_amdgcn_s_barrier();
    asm volatile("" ::: "memory");

    bf16x8 af[4][2], bfr[4][2];

#define MID_BARRIER()                                      \
    asm volatile("" ::: "memory");                         \
    __builtin_amdgcn_s_barrier();                          \
    asm volatile("s_waitcnt lgkmcnt(0)" ::: "memory");     \
    __builtin_amdgcn_sched_barrier(0);

#define END_BARRIER()                                      \
    asm volatile("" ::: "memory");                         \
    __builtin_amdgcn_s_barrier();                          \
    asm volatile("" ::: "memory");

    for (int tt = 0; tt < NT; ++tt) {
        const int buf = tt & 1;

        // ph0: reads A m0-3 + B n0-1; stage A-h0(tt+1); MFMA Q0
#pragma unroll
        for (int m = 0; m < 4; ++m) { af[m][0] = LDA(buf, m, 0); af[m][1] = LDA(buf, m, 1); }
#pragma unroll
        for (int n = 0; n < 2; ++n) { bfr[n][0] = LDB(buf, n, 0); bfr[n][1] = LDB(buf, n, 1); }
        if (tt + 1 < NT) STAGE(tt + 1, 0, 0);
        MID_BARRIER();
        __builtin_amdgcn_s_setprio(1);
#pragma unroll
        for (int m = 0; m < 4; ++m)
#pragma unroll
            for (int n = 0; n < 2; ++n)
#pragma unroll
                for (int kk = 0; kk < 2; ++kk)
                    acc[m][n] = __builtin_amdgcn_mfma_f32_16x16x32_bf16(af[m][kk], bfr[n][kk], acc[m][n], 0, 0, 0);
        __builtin_amdgcn_s_setprio(0);
        END_BARRIER();

        // ph1: reads B n2-3; stage A-h1(tt+1); MFMA Q1
#pragma unroll
        for (int n = 0; n < 2; ++n) { bfr[2 + n][0] = LDB(buf, 2 + n, 0); bfr[2 + n][1] = LDB(buf, 2 + n, 1); }
        if (tt + 1 < NT) STAGE(tt + 1, 0, 1);
        MID_BARRIER();
        __builtin_amdgcn_s_setprio(1);
#pragma unroll
        for (int m = 0; m < 4; ++m)
#pragma unroll
            for (int n = 0; n < 2; ++n)
#pragma unroll
                for (int kk = 0; kk < 2; ++kk)
                    acc[m][2 + n] = __builtin_amdgcn_mfma_f32_16x16x32_bf16(af[m][kk], bfr[2 + n][kk], acc[m][2 + n], 0, 0, 0);
        __builtin_amdgcn_s_setprio(0);
        END_BARRIER();

        // ph2: reads A m4-7; stage B-h0(tt+2); MFMA Q2
#pragma unroll
        for (int m = 0; m < 4; ++m) { af[m][0] = LDA(buf, 4 + m, 0); af[m][1] = LDA(buf, 4 + m, 1); }
        if (tt + 2 < NT) STAGE(tt + 2, 1, 0);
        MID_BARRIER();
        __builtin_amdgcn_s_setprio(1);
#pragma unroll
        for (int m = 0; m < 4; ++m)
#pragma unroll
            for (int n = 0; n < 2; ++n)
#pragma unroll
                for (int kk = 0; kk < 2; ++kk)
                    acc[4 + m][n] = __builtin_amdgcn_mfma_f32_16x16x32_bf16(af[m][kk], bfr[n][kk], acc[4 + m][n], 0, 0, 0);
        __builtin_amdgcn_s_setprio(0);
        END_BARRIER();

        // ph3: stage B-h1(tt+2); MFMA Q3; vmcnt gate
        if (tt + 2 < NT) STAGE(tt + 2, 1, 1);
        asm volatile("" ::: "memory");
        __builtin_amdgcn_s_barrier();
        __builtin_amdgcn_sched_barrier(0);
        __builtin_amdgcn_s_setprio(1);
#pragma unroll
        for (int m = 0; m < 4; ++m)
#pragma unroll
            for (int n = 0; n < 2; ++n)
#pragma unroll
                for (int kk = 0; kk < 2; ++kk)
                    acc[4 + m][2 + n] = __builtin_amdgcn_mfma_f32_16x16x32_bf16(af[m][kk], bfr[2 + n][kk], acc[4 + m][2 + n], 0, 0, 0);
        __builtin_amdgcn_s_setprio(0);
        if (tt < NT - 2)       asm volatile("s_waitcnt vmcnt(4)" ::: "memory");
        else if (tt == NT - 2) asm volatile("s_waitcnt vmcnt(0)" ::: "memory");
        END_BARRIER();
    }
#undef MID_BARRIER
#undef END_BARRIER

    // epilogue: relu, fp32 direct
    const int rowOff = (lane >> 4) * 4;
#pragma unroll
    for (int m = 0; m < 8; ++m)
#pragma unroll
        for (int n = 0; n < 4; ++n)
#pragma unroll
            for (int r = 0; r < 4; ++r)
                outf[(size_t)(mt * 256 + wr * 128 + m * 16 + rowOff + r) * NTOT
                     + nt * 256 + wc * 64 + n * 16 + lr] = fmaxf(acc[m][n][r], 0.f);
}

// ---------- per-batch: sim -> mask -> softmax -> relation + agg ----------
__global__ __launch_bounds__(256)
void relation_kernel(const unsigned short* __restrict__ TP,   // [M,512] bf16: theta|phi
                     const float* __restrict__ boxes,         // [M,4]
                     const float* __restrict__ X,             // [M,1024] fp32
                     unsigned short* __restrict__ aggb,       // [M,1024] bf16 out
                     float* __restrict__ relout) {            // [BT,12,12] fp32
    __shared__ float th[12][260];
    __shared__ float ph[12][260];
    __shared__ unsigned short xls[12 * 1024];
    __shared__ float cx[12], cy[12];
    __shared__ float sim[12][12];
    __shared__ float rel[12][12];

    const int b = blockIdx.x;
    const int t = threadIdx.x;

    if (t < 12) {
        const float* bx = boxes + ((size_t)b * 12 + t) * 4;
        cx[t] = (bx[0] + bx[2]) * 0.5f;
        cy[t] = (bx[1] + bx[3]) * 0.5f;
    }
    const uint4* tp4 = (const uint4*)(TP + (size_t)b * 6144);
    for (int c = t; c < 768; c += 256) {
        uint4 v = tp4[c];
        const unsigned short* pv = (const unsigned short*)&v;
        const int n = c >> 6;
        const int c0 = (c & 63) << 3;
        if (c0 < 256) {
#pragma unroll
            for (int jj = 0; jj < 8; ++jj) th[n][c0 + jj] = bf2f(pv[jj]);
        } else {
#pragma unroll
            for (int jj = 0; jj < 8; ++jj) ph[n][c0 - 256 + jj] = bf2f(pv[jj]);
        }
    }
    // stage x tile from fp32, convert to bf16 (bit-identical to the old cast path)
    const float4* x4 = (const float4*)(X + (size_t)b * 12288);
    for (int c = t; c < 3072; c += 256) {
        float4 v = x4[c];
        ushort4 o;
        o.x = f2bf(v.x); o.y = f2bf(v.y); o.z = f2bf(v.z); o.w = f2bf(v.w);
        *reinterpret_cast<ushort4*>(&xls[c * 4]) = o;
    }
    __syncthreads();

    if (t < 144) {
        const int n = t / 12, m = t - (t / 12) * 12;
        float a = 0.f;
#pragma unroll 8
        for (int r = 0; r < 256; ++r) a += th[n][r] * ph[m][r];
        const float dx = cx[n] - cx[m], dy = cy[n] - cy[m];
        const float d2 = dx * dx + dy * dy;
        const float thr = 31.4f;  // POS_THRESHOLD * OW
        sim[n][m] = (d2 > thr * thr) ? -__builtin_inff() : a * 0.0625f;
    }
    __syncthreads();

    if (t < 12) {
        float mx = -__builtin_inff();
#pragma unroll
        for (int m = 0; m < 12; ++m) mx = fmaxf(mx, sim[t][m]);
        float e[12]; float s = 0.f;
#pragma unroll
        for (int m = 0; m < 12; ++m) { e[m] = expf(sim[t][m] - mx); s += e[m]; }
        const float inv = 1.f / s;
#pragma unroll
        for (int m = 0; m < 12; ++m) {
            const float r = e[m] * inv;
            rel[t][m] = r;
            relout[(size_t)b * 144 + t * 12 + m] = r;
        }
    }
    __syncthreads();

    unsigned short* aggp = aggb + (size_t)b * 12288;
    for (int f = t; f < 1024; f += 256) {
        float xv[12];
#pragma unroll
        for (int m = 0; m < 12; ++m) xv[m] = bf2f(xls[m * 1024 + f]);
#pragma unroll
        for (int n = 0; n < 12; ++n) {
            float a = 0.f;
#pragma unroll
            for (int m = 0; m < 12; ++m) a += rel[n][m] * xv[m];
            aggp[n * 1024 + f] = f2bf(a);
        }
    }
}

// ---------- launcher ----------
extern "C" void kernel_launch(void* const* d_in, const int* in_sizes, int n_in,
                              void* d_out, int out_size, void* d_ws, size_t ws_size,
                              hipStream_t stream) {
    const float* x     = (const float*)d_in[0];  // [4096,12,1024] fp32
    const float* boxes = (const float*)d_in[1];  // [49152,4]
    const float* Wth   = (const float*)d_in[2];  // [256,1024]
    const float* bth   = (const float*)d_in[3];  // [256]
    const float* Wph   = (const float*)d_in[4];  // [256,1024]
    const float* bph   = (const float*)d_in[5];  // [256]
    const float* Wg    = (const float*)d_in[6];  // [1024,1024]
    float* out = (float*)d_out;                  // 49152*1024 out | 4096*144 relation

    const int M = 49152;
    const size_t XE = (size_t)M * 1024;

    char* ws = (char*)d_ws;
    unsigned short* aggb = (unsigned short*)ws;                 // [M,1024] bf16 agg
    unsigned short* TP   = (unsigned short*)(ws + 100663296);   // [M,512] bf16 theta|phi
    unsigned short* Wcat = (unsigned short*)(ws + 150994944);   // [512,1024] bf16
    unsigned short* Wgb  = (unsigned short*)(ws + 152043520);   // [1024,1024] bf16

    cast3_kernel<<<1536, 256, 0, stream>>>(Wth, Wph, Wg, Wcat, Wcat + 262144, Wgb);

    // gemm0h: fused cast via fp32 LDS staging; 384 M-tiles x NTI=2 -> 768 blocks
    gemm0h<512, 2><<<dim3(768), 512, 0, stream>>>(x, Wcat, bth, bph, TP);

    relation_kernel<<<4096, 256, 0, stream>>>(TP, boxes, x, aggb, out + XE);

    // gemm1: 192 M-tiles (24/XCD) x NTI=4 -> 768 blocks (round-7 exact)
    gemm_bt<1024, 4><<<dim3(768), 512, 0, stream>>>(aggb, Wgb, out);
}

// Round 10
// 284.919 us; speedup vs baseline: 1.1989x; 1.1154x over previous
//
#include <hip/hip_runtime.h>
#include <stdint.h>

// ---------- types ----------
typedef __attribute__((ext_vector_type(8))) __bf16 bf16x8;
typedef __attribute__((ext_vector_type(4))) float   f32x4;

__device__ __forceinline__ float bf2f(unsigned short u) {
    union { unsigned int i; float f; } v; v.i = ((unsigned int)u) << 16; return v.f;
}
__device__ __forceinline__ unsigned short f2bf(float f) {  // round-to-nearest-even
    unsigned int x = __builtin_bit_cast(unsigned int, f);
    x += 0x7FFFu + ((x >> 16) & 1u);
    return (unsigned short)(x >> 16);
}

// ---------- fp32 -> bf16 cast (vectorized, grid-stride) ----------
__global__ __launch_bounds__(256) void cast_kernel(const float* __restrict__ src,
                                                   unsigned short* __restrict__ dst, int n4) {
    int i = blockIdx.x * blockDim.x + threadIdx.x;
    int stride = gridDim.x * blockDim.x;
    const float4* s4 = (const float4*)src;
    ushort4* d4 = (ushort4*)dst;
    for (; i < n4; i += stride) {
        float4 v = s4[i];
        ushort4 o;
        o.x = f2bf(v.x); o.y = f2bf(v.y); o.z = f2bf(v.z); o.w = f2bf(v.w);
        d4[i] = o;
    }
}

// ---------- fused 3-weight cast (Wth 256x1024, Wph 256x1024, Wg 1024x1024) ----------
__global__ __launch_bounds__(256) void cast3_kernel(const float* __restrict__ a,
                                                    const float* __restrict__ b,
                                                    const float* __restrict__ c,
                                                    unsigned short* __restrict__ dA,
                                                    unsigned short* __restrict__ dB,
                                                    unsigned short* __restrict__ dC) {
    const int i = blockIdx.x * blockDim.x + threadIdx.x;   // 0..393215 (x4 elems)
    const float4* s4; ushort4* d4; int off;
    if (i < 65536)       { s4 = (const float4*)a; d4 = (ushort4*)dA; off = i; }
    else if (i < 131072) { s4 = (const float4*)b; d4 = (ushort4*)dB; off = i - 65536; }
    else                 { s4 = (const float4*)c; d4 = (ushort4*)dC; off = i - 131072; }
    float4 v = s4[off];
    ushort4 o;
    o.x = f2bf(v.x); o.y = f2bf(v.y); o.z = f2bf(v.z); o.w = f2bf(v.w);
    d4[off] = o;
}

// ---------- GEMM A: 128x256 tile (gemm0, round-7 exact) ----------
template<int NTOT, int NTI>
__global__ __launch_bounds__(512, 2)
void gemm_bt128(const unsigned short* __restrict__ A,
                const unsigned short* __restrict__ W,
                const float* __restrict__ bias0,
                const float* __restrict__ bias1,
                unsigned short* __restrict__ outb) {
    constexpr int K  = 1024;
    constexpr int NT = 16;                 // K-tiles of 64
    __shared__ unsigned short lds[49152];  // 2 x (A 128x64 + B 256x64) = 96 KB

    const int t    = threadIdx.x;
    const int wave = t >> 6;
    const int lane = t & 63;

    const int bid = blockIdx.x;
    const int xcd = bid & 7;               // HW round-robins blocks over 8 XCDs
    const int j   = bid >> 3;
    const int mt  = xcd * 48 + j / NTI;    // 384 M-tiles, 48 per XCD
    const int nt  = j % NTI;

    const int wr = wave >> 2;              // 0..1 : rows wr*64..
    const int wc = wave & 3;               // 0..3 : cols wc*64..

    const size_t aBase = (size_t)mt * 128 * K;
    const size_t bBase = (size_t)nt * 256 * K;

    const int srow = t >> 3;                          // 0..63
    const int scol = ((t & 7) ^ (srow & 7)) << 3;     // element offset
    const unsigned short* gA = A + aBase + (size_t)srow * K + scol;
    const unsigned short* gB = W + bBase + (size_t)srow * K + scol;

    auto STAGE_A = [&](int tile) {                     // 2 gloads: rows 0-63, 64-127
        unsigned short* lb = lds + (tile & 1) * 24576;
        const unsigned short* gp = gA + tile * 64;
#pragma unroll
        for (int g = 0; g < 2; ++g)
            __builtin_amdgcn_global_load_lds(
                (const __attribute__((address_space(1))) void*)(gp + (size_t)(g * 64) * K),
                (__attribute__((address_space(3))) void*)(lb + g * 4096 + wave * 512), 16, 0, 0);
    };
    auto STAGE_B = [&](int tile) {                     // 4 gloads: rows 0..255
        unsigned short* lb = lds + (tile & 1) * 24576 + 8192;
        const unsigned short* gp = gB + tile * 64;
#pragma unroll
        for (int g = 0; g < 4; ++g)
            __builtin_amdgcn_global_load_lds(
                (const __attribute__((address_space(1))) void*)(gp + (size_t)(g * 64) * K),
                (__attribute__((address_space(3))) void*)(lb + g * 4096 + wave * 512), 16, 0, 0);
    };

    const int lr  = lane & 15;
    const int lkc = lane >> 4;
    auto LDA = [&](int buf, int mi, int kk) -> bf16x8 {
        const int row = wr * 64 + mi * 16 + lr;
        const int ch  = (kk * 4 + lkc) ^ (row & 7);
        return *reinterpret_cast<const bf16x8*>(&lds[buf * 24576 + row * 64 + ch * 8]);
    };
    auto LDB = [&](int buf, int ni, int kk) -> bf16x8 {
        const int row = wc * 64 + ni * 16 + lr;
        const int ch  = (kk * 4 + lkc) ^ (row & 7);
        return *reinterpret_cast<const bf16x8*>(&lds[buf * 24576 + 8192 + row * 64 + ch * 8]);
    };

    f32x4 acc[4][4];
#pragma unroll
    for (int m = 0; m < 4; ++m)
#pragma unroll
        for (int n = 0; n < 4; ++n) acc[m][n] = f32x4{0.f, 0.f, 0.f, 0.f};

    // prologue FIFO: A0(2), B0(4), B1(4) -> wait-to-4 lands tile 0, B1 in flight
    STAGE_A(0); STAGE_B(0); STAGE_B(1);
    asm volatile("s_waitcnt vmcnt(4)" ::: "memory");
    __builtin_amdgcn_s_barrier();
    asm volatile("" ::: "memory");

    bf16x8 af[4][2], b0[2][2], b1[2][2];

    for (int tt = 0; tt < NT; ++tt) {
        const int buf = tt & 1;

        // ---- ph0: reads A m0-3 (8) + B n0-1 (4); stage A(t+1) (buf^1, safe); MFMA Q0 ----
#pragma unroll
        for (int m = 0; m < 4; ++m) { af[m][0] = LDA(buf, m, 0); af[m][1] = LDA(buf, m, 1); }
#pragma unroll
        for (int n = 0; n < 2; ++n) { b0[n][0] = LDB(buf, n, 0); b0[n][1] = LDB(buf, n, 1); }
        if (tt + 1 < NT) STAGE_A(tt + 1);
        asm volatile("" ::: "memory");
        __builtin_amdgcn_s_barrier();
        asm volatile("s_waitcnt lgkmcnt(0)" ::: "memory");
        __builtin_amdgcn_sched_barrier(0);
        __builtin_amdgcn_s_setprio(1);
#pragma unroll
        for (int m = 0; m < 4; ++m)
#pragma unroll
            for (int n = 0; n < 2; ++n)
#pragma unroll
                for (int kk = 0; kk < 2; ++kk)
                    acc[m][n] = __builtin_amdgcn_mfma_f32_16x16x32_bf16(af[m][kk], b0[n][kk], acc[m][n], 0, 0, 0);
        __builtin_amdgcn_s_setprio(0);
        asm volatile("" ::: "memory");
        __builtin_amdgcn_s_barrier();
        asm volatile("" ::: "memory");

        // ---- ph1: reads B n2-3 (4); MFMA Q1; then stage B(t+2); gate ----
#pragma unroll
        for (int n = 0; n < 2; ++n) { b1[n][0] = LDB(buf, 2 + n, 0); b1[n][1] = LDB(buf, 2 + n, 1); }
        asm volatile("" ::: "memory");
        __builtin_amdgcn_s_barrier();
        asm volatile("s_waitcnt lgkmcnt(0)" ::: "memory");
        __builtin_amdgcn_sched_barrier(0);
        __builtin_amdgcn_s_setprio(1);
#pragma unroll
        for (int m = 0; m < 4; ++m)
#pragma unroll
            for (int n = 0; n < 2; ++n)
#pragma unroll
                for (int kk = 0; kk < 2; ++kk)
                    acc[m][2 + n] = __builtin_amdgcn_mfma_f32_16x16x32_bf16(af[m][kk], b1[n][kk], acc[m][2 + n], 0, 0, 0);
        __builtin_amdgcn_s_setprio(0);
        __builtin_amdgcn_sched_barrier(0);
        if (tt + 2 < NT) STAGE_B(tt + 2);
        // gate: FIFO [B(t+1)x4, A(t+1)x2, B(t+2)x4] -> wait-to-4 = tile t+1 landed
        if (tt < NT - 2)       asm volatile("s_waitcnt vmcnt(4)" ::: "memory");
        else if (tt == NT - 2) asm volatile("s_waitcnt vmcnt(0)" ::: "memory");
        asm volatile("" ::: "memory");
        __builtin_amdgcn_s_barrier();
        asm volatile("" ::: "memory");
    }

    // -------- epilogue: acc -> LDS (single pass, 72 KB) -> coalesced bf16 stores --------
    const int rowOff = (lane >> 4) * 4;   // C/D: col = lane&15, row = rowOff + r
    unsigned short* lu = lds;             // 8 regions x 64 x 72 shorts
#pragma unroll
    for (int mq = 0; mq < 4; ++mq)
#pragma unroll
        for (int n = 0; n < 4; ++n) {
            const int gc = nt * 256 + wc * 64 + n * 16 + lr;
            const float bv = (gc < 256) ? bias0[gc] : bias1[gc - 256];
#pragma unroll
            for (int r = 0; r < 4; ++r)
                lu[wave * 4608 + (mq * 16 + rowOff + r) * 72 + n * 16 + lr] =
                    f2bf(acc[mq][n][r] + bv);
        }
    __syncthreads();
#pragma unroll
    for (int it = 0; it < 8; ++it) {      // 128 rows x 256 cols bf16
        const int flat = it * 4096 + t * 8;   // shorts
        const int row  = flat >> 8;           // 0..127
        const int col  = flat & 255;
        const int wv   = (row >> 6) * 4 + (col >> 6);
        uint4 v = *reinterpret_cast<const uint4*>(&lu[wv * 4608 + (row & 63) * 72 + (col & 63)]);
        *reinterpret_cast<uint4*>(outb + (size_t)(mt * 128 + row) * NTOT + nt * 256 + col) = v;
    }
}

// ---------- GEMM B: 256x256 tile (gemm1, round-4/7 variant, relu + fp32 out) ----------
template<int NTOT, int NTI>
__global__ __launch_bounds__(512, 2)
void gemm_bt(const unsigned short* __restrict__ A,
             const unsigned short* __restrict__ W,
             float* __restrict__ outf) {
    constexpr int K  = 1024;
    constexpr int NT = 16;                 // K-tiles of 64
    __shared__ unsigned short lds[65536];  // 2 x (A 256x64 + B 256x64) = 128 KB

    const int t    = threadIdx.x;
    const int wave = t >> 6;
    const int lane = t & 63;

    const int bid = blockIdx.x;
    const int xcd = bid & 7;
    const int j   = bid >> 3;
    const int mt  = xcd * 24 + j / NTI;    // 192 M-tiles, 24 per XCD
    const int nt  = j % NTI;

    const int wr = wave >> 2;              // 0..1 : M half (rows wr*128..)
    const int wc = wave & 3;               // 0..3 : N quarter (cols wc*64..)

    const size_t aBase = (size_t)mt * 256 * K;
    const size_t bBase = (size_t)nt * 256 * K;

    const int srow = t >> 3;                          // 0..63
    const int scol = ((t & 7) ^ (srow & 7)) << 3;     // element offset
    const unsigned short* gA = A + aBase + (size_t)srow * K + scol;
    const unsigned short* gB = W + bBase + (size_t)srow * K + scol;

    auto STAGE = [&](int tile, int isB, int half) {
        unsigned short* lb = lds + (tile & 1) * 32768 + isB * 16384 + half * 8192;
        const unsigned short* gp = (isB ? gB : gA) + (size_t)(half * 128) * K + tile * 64;
#pragma unroll
        for (int g = 0; g < 2; ++g)
            __builtin_amdgcn_global_load_lds(
                (const __attribute__((address_space(1))) void*)(gp + (size_t)(g * 64) * K),
                (__attribute__((address_space(3))) void*)(lb + g * 4096 + wave * 512), 16, 0, 0);
    };

    const int lr  = lane & 15;
    const int lkc = lane >> 4;
    auto LDA = [&](int buf, int mi, int kk) -> bf16x8 {
        const int row = wr * 128 + mi * 16 + lr;
        const int ch  = (kk * 4 + lkc) ^ (row & 7);
        return *reinterpret_cast<const bf16x8*>(&lds[buf * 32768 + row * 64 + ch * 8]);
    };
    auto LDB = [&](int buf, int ni, int kk) -> bf16x8 {
        const int row = wc * 64 + ni * 16 + lr;
        const int ch  = (kk * 4 + lkc) ^ (row & 7);
        return *reinterpret_cast<const bf16x8*>(&lds[buf * 32768 + 16384 + row * 64 + ch * 8]);
    };

    f32x4 acc[8][4];
#pragma unroll
    for (int m = 0; m < 8; ++m)
#pragma unroll
        for (int n = 0; n < 4; ++n) acc[m][n] = f32x4{0.f, 0.f, 0.f, 0.f};

    // prologue: B(0), A(0), B(1)
    STAGE(0, 1, 0); STAGE(0, 1, 1);
    STAGE(0, 0, 0); STAGE(0, 0, 1);
    STAGE(1, 1, 0); STAGE(1, 1, 1);
    asm volatile("s_waitcnt vmcnt(4)" ::: "memory");
    __builtin_amdgcn_s_barrier();
    asm volatile("" ::: "memory");

    bf16x8 af[4][2], bfr[4][2];

#define MID_BARRIER()                                      \
    asm volatile("" ::: "memory");                         \
    __builtin_amdgcn_s_barrier();                          \
    asm volatile("s_waitcnt lgkmcnt(0)" ::: "memory");     \
    __builtin_amdgcn_sched_barrier(0);

#define END_BARRIER()                                      \
    asm volatile("" ::: "memory");                         \
    __builtin_amdgcn_s_barrier();                          \
    asm volatile("" ::: "memory");

    for (int tt = 0; tt < NT; ++tt) {
        const int buf = tt & 1;

        // ph0: reads A m0-3 + B n0-1; stage A-h0(tt+1); MFMA Q0
#pragma unroll
        for (int m = 0; m < 4; ++m) { af[m][0] = LDA(buf, m, 0); af[m][1] = LDA(buf, m, 1); }
#pragma unroll
        for (int n = 0; n < 2; ++n) { bfr[n][0] = LDB(buf, n, 0); bfr[n][1] = LDB(buf, n, 1); }
        if (tt + 1 < NT) STAGE(tt + 1, 0, 0);
        MID_BARRIER();
        __builtin_amdgcn_s_setprio(1);
#pragma unroll
        for (int m = 0; m < 4; ++m)
#pragma unroll
            for (int n = 0; n < 2; ++n)
#pragma unroll
                for (int kk = 0; kk < 2; ++kk)
                    acc[m][n] = __builtin_amdgcn_mfma_f32_16x16x32_bf16(af[m][kk], bfr[n][kk], acc[m][n], 0, 0, 0);
        __builtin_amdgcn_s_setprio(0);
        END_BARRIER();

        // ph1: reads B n2-3; stage A-h1(tt+1); MFMA Q1
#pragma unroll
        for (int n = 0; n < 2; ++n) { bfr[2 + n][0] = LDB(buf, 2 + n, 0); bfr[2 + n][1] = LDB(buf, 2 + n, 1); }
        if (tt + 1 < NT) STAGE(tt + 1, 0, 1);
        MID_BARRIER();
        __builtin_amdgcn_s_setprio(1);
#pragma unroll
        for (int m = 0; m < 4; ++m)
#pragma unroll
            for (int n = 0; n < 2; ++n)
#pragma unroll
                for (int kk = 0; kk < 2; ++kk)
                    acc[m][2 + n] = __builtin_amdgcn_mfma_f32_16x16x32_bf16(af[m][kk], bfr[2 + n][kk], acc[m][2 + n], 0, 0, 0);
        __builtin_amdgcn_s_setprio(0);
        END_BARRIER();

        // ph2: reads A m4-7; stage B-h0(tt+2); MFMA Q2
#pragma unroll
        for (int m = 0; m < 4; ++m) { af[m][0] = LDA(buf, 4 + m, 0); af[m][1] = LDA(buf, 4 + m, 1); }
        if (tt + 2 < NT) STAGE(tt + 2, 1, 0);
        MID_BARRIER();
        __builtin_amdgcn_s_setprio(1);
#pragma unroll
        for (int m = 0; m < 4; ++m)
#pragma unroll
            for (int n = 0; n < 2; ++n)
#pragma unroll
                for (int kk = 0; kk < 2; ++kk)
                    acc[4 + m][n] = __builtin_amdgcn_mfma_f32_16x16x32_bf16(af[m][kk], bfr[n][kk], acc[4 + m][n], 0, 0, 0);
        __builtin_amdgcn_s_setprio(0);
        END_BARRIER();

        // ph3: stage B-h1(tt+2); MFMA Q3; vmcnt gate
        if (tt + 2 < NT) STAGE(tt + 2, 1, 1);
        asm volatile("" ::: "memory");
        __builtin_amdgcn_s_barrier();
        __builtin_amdgcn_sched_barrier(0);
        __builtin_amdgcn_s_setprio(1);
#pragma unroll
        for (int m = 0; m < 4; ++m)
#pragma unroll
            for (int n = 0; n < 2; ++n)
#pragma unroll
                for (int kk = 0; kk < 2; ++kk)
                    acc[4 + m][2 + n] = __builtin_amdgcn_mfma_f32_16x16x32_bf16(af[m][kk], bfr[2 + n][kk], acc[4 + m][2 + n], 0, 0, 0);
        __builtin_amdgcn_s_setprio(0);
        if (tt < NT - 2)       asm volatile("s_waitcnt vmcnt(4)" ::: "memory");
        else if (tt == NT - 2) asm volatile("s_waitcnt vmcnt(0)" ::: "memory");
        END_BARRIER();
    }
#undef MID_BARRIER
#undef END_BARRIER

    // epilogue: relu, fp32 direct
    const int rowOff = (lane >> 4) * 4;
#pragma unroll
    for (int m = 0; m < 8; ++m)
#pragma unroll
        for (int n = 0; n < 4; ++n)
#pragma unroll
            for (int r = 0; r < 4; ++r)
                outf[(size_t)(mt * 256 + wr * 128 + m * 16 + rowOff + r) * NTOT
                     + nt * 256 + wc * 64 + n * 16 + lr] = fmaxf(acc[m][n][r], 0.f);
}

// ---------- per-batch: sim -> mask -> softmax -> relation + agg (in-place over x_bf16) ----------
// Vectorized LDS access: float4 dot reads, ushort4 agg reads + packed stores.
__global__ __launch_bounds__(256)
void relation_kernel(const unsigned short* __restrict__ TP,   // [M,512] bf16: theta|phi
                     const float* __restrict__ boxes,         // [M,4]
                     unsigned short* __restrict__ xagg,       // [M,1024] bf16 in, agg out (aliased)
                     float* __restrict__ relout) {            // [BT,12,12] fp32
    __shared__ float th[12][260];   // row stride 1040 B (16-aligned), +4 pad
    __shared__ float ph[12][260];
    __shared__ unsigned short xls[12 * 1024];
    __shared__ float cx[12], cy[12];
    __shared__ float sim[12][12];
    __shared__ float rel[12][12];

    const int b = blockIdx.x;
    const int t = threadIdx.x;

    if (t < 12) {
        const float* bx = boxes + ((size_t)b * 12 + t) * 4;
        cx[t] = (bx[0] + bx[2]) * 0.5f;
        cy[t] = (bx[1] + bx[3]) * 0.5f;
    }
    const uint4* tp4 = (const uint4*)(TP + (size_t)b * 6144);
    for (int c = t; c < 768; c += 256) {
        uint4 v = tp4[c];
        const unsigned short* pv = (const unsigned short*)&v;
        const int n = c >> 6;
        const int c0 = (c & 63) << 3;
        if (c0 < 256) {
#pragma unroll
            for (int jj = 0; jj < 8; ++jj) th[n][c0 + jj] = bf2f(pv[jj]);
        } else {
#pragma unroll
            for (int jj = 0; jj < 8; ++jj) ph[n][c0 - 256 + jj] = bf2f(pv[jj]);
        }
    }
    const uint4* x4 = (const uint4*)(xagg + (size_t)b * 12288);
    uint4* xl4 = (uint4*)xls;
    for (int c = t; c < 1536; c += 256) xl4[c] = x4[c];
    __syncthreads();

    if (t < 144) {
        const int n = t / 12, m = t - (t / 12) * 12;
        const float4* tn = (const float4*)&th[n][0];
        const float4* pm = (const float4*)&ph[m][0];
        float a = 0.f;
#pragma unroll 8
        for (int r = 0; r < 64; ++r) {   // same accumulation order as scalar loop
            float4 av = tn[r], bv4 = pm[r];
            a += av.x * bv4.x; a += av.y * bv4.y; a += av.z * bv4.z; a += av.w * bv4.w;
        }
        const float dx = cx[n] - cx[m], dy = cy[n] - cy[m];
        const float d2 = dx * dx + dy * dy;
        const float thr = 31.4f;  // POS_THRESHOLD * OW
        sim[n][m] = (d2 > thr * thr) ? -__builtin_inff() : a * 0.0625f;
    }
    __syncthreads();

    if (t < 12) {
        float mx = -__builtin_inff();
#pragma unroll
        for (int m = 0; m < 12; ++m) mx = fmaxf(mx, sim[t][m]);
        float e[12]; float s = 0.f;
#pragma unroll
        for (int m = 0; m < 12; ++m) { e[m] = expf(sim[t][m] - mx); s += e[m]; }
        const float inv = 1.f / s;
#pragma unroll
        for (int m = 0; m < 12; ++m) {
            const float r = e[m] * inv;
            rel[t][m] = r;
            relout[(size_t)b * 144 + t * 12 + m] = r;
        }
    }
    __syncthreads();

    // agg[n][f] = sum_m rel[n][m] * x[m][f]  -> bf16, in place
    // each thread owns 4 consecutive f: ushort4 LDS reads, ushort4 global stores
    unsigned short* aggp = xagg + (size_t)b * 12288;
    {
        const int f0 = t * 4;
        float xv[12][4];
#pragma unroll
        for (int m = 0; m < 12; ++m) {
            ushort4 u = *reinterpret_cast<const ushort4*>(&xls[m * 1024 + f0]);
            xv[m][0] = bf2f(u.x); xv[m][1] = bf2f(u.y);
            xv[m][2] = bf2f(u.z); xv[m][3] = bf2f(u.w);
        }
        float rl[12];
#pragma unroll
        for (int n = 0; n < 12; ++n) {
#pragma unroll
            for (int m = 0; m < 12; ++m) rl[m] = rel[n][m];
            ushort4 o;
            float a0 = 0.f, a1 = 0.f, a2 = 0.f, a3 = 0.f;
#pragma unroll
            for (int m = 0; m < 12; ++m) {
                a0 += rl[m] * xv[m][0];
                a1 += rl[m] * xv[m][1];
                a2 += rl[m] * xv[m][2];
                a3 += rl[m] * xv[m][3];
            }
            o.x = f2bf(a0); o.y = f2bf(a1); o.z = f2bf(a2); o.w = f2bf(a3);
            *reinterpret_cast<ushort4*>(&aggp[n * 1024 + f0]) = o;
        }
    }
}

// ---------- launcher ----------
extern "C" void kernel_launch(void* const* d_in, const int* in_sizes, int n_in,
                              void* d_out, int out_size, void* d_ws, size_t ws_size,
                              hipStream_t stream) {
    const float* x     = (const float*)d_in[0];  // [4096,12,1024] fp32
    const float* boxes = (const float*)d_in[1];  // [49152,4]
    const float* Wth   = (const float*)d_in[2];  // [256,1024]
    const float* bth   = (const float*)d_in[3];  // [256]
    const float* Wph   = (const float*)d_in[4];  // [256,1024]
    const float* bph   = (const float*)d_in[5];  // [256]
    const float* Wg    = (const float*)d_in[6];  // [1024,1024]
    float* out = (float*)d_out;                  // 49152*1024 out | 4096*144 relation

    const int M = 49152;
    const size_t XE = (size_t)M * 1024;

    char* ws = (char*)d_ws;
    unsigned short* xb   = (unsigned short*)ws;                 // bf16 x, later agg (in place)
    unsigned short* TP   = (unsigned short*)(ws + 100663296);   // [M,512] bf16 theta|phi
    unsigned short* Wcat = (unsigned short*)(ws + 150994944);   // [512,1024] bf16
    unsigned short* Wgb  = (unsigned short*)(ws + 152043520);   // [1024,1024] bf16

    cast_kernel<<<2048, 256, 0, stream>>>(x, xb, (int)(XE / 4));
    cast3_kernel<<<1536, 256, 0, stream>>>(Wth, Wph, Wg, Wcat, Wcat + 262144, Wgb);

    // gemm0: 384 M-tiles (48/XCD) x NTI=2 -> 768 blocks = 3.0 even grid-waves
    gemm_bt128<512, 2><<<dim3(768), 512, 0, stream>>>(xb, Wcat, bth, bph, TP);

    relation_kernel<<<4096, 256, 0, stream>>>(TP, boxes, xb, out + XE);

    // gemm1: 192 M-tiles (24/XCD) x NTI=4 -> 768 blocks
    gemm_bt<1024, 4><<<dim3(768), 512, 0, stream>>>(xb, Wgb, out);
}

// Round 11
// 283.242 us; speedup vs baseline: 1.2060x; 1.0059x over previous
//
#include <hip/hip_runtime.h>
#include <stdint.h>

// ---------- types ----------
typedef __attribute__((ext_vector_type(8))) __bf16 bf16x8;
typedef __attribute__((ext_vector_type(4))) float   f32x4;

__device__ __forceinline__ float bf2f(unsigned short u) {
    union { unsigned int i; float f; } v; v.i = ((unsigned int)u) << 16; return v.f;
}
__device__ __forceinline__ unsigned short f2bf(float f) {  // round-to-nearest-even
    unsigned int x = __builtin_bit_cast(unsigned int, f);
    x += 0x7FFFu + ((x >> 16) & 1u);
    return (unsigned short)(x >> 16);
}

// ---------- fp32 -> bf16 cast (vectorized, grid-stride) ----------
__global__ __launch_bounds__(256) void cast_kernel(const float* __restrict__ src,
                                                   unsigned short* __restrict__ dst, int n4) {
    int i = blockIdx.x * blockDim.x + threadIdx.x;
    int stride = gridDim.x * blockDim.x;
    const float4* s4 = (const float4*)src;
    ushort4* d4 = (ushort4*)dst;
    for (; i < n4; i += stride) {
        float4 v = s4[i];
        ushort4 o;
        o.x = f2bf(v.x); o.y = f2bf(v.y); o.z = f2bf(v.z); o.w = f2bf(v.w);
        d4[i] = o;
    }
}

// ---------- fused 3-weight cast (Wth 256x1024, Wph 256x1024, Wg 1024x1024) ----------
__global__ __launch_bounds__(256) void cast3_kernel(const float* __restrict__ a,
                                                    const float* __restrict__ b,
                                                    const float* __restrict__ c,
                                                    unsigned short* __restrict__ dA,
                                                    unsigned short* __restrict__ dB,
                                                    unsigned short* __restrict__ dC) {
    const int i = blockIdx.x * blockDim.x + threadIdx.x;   // 0..393215 (x4 elems)
    const float4* s4; ushort4* d4; int off;
    if (i < 65536)       { s4 = (const float4*)a; d4 = (ushort4*)dA; off = i; }
    else if (i < 131072) { s4 = (const float4*)b; d4 = (ushort4*)dB; off = i - 65536; }
    else                 { s4 = (const float4*)c; d4 = (ushort4*)dC; off = i - 131072; }
    float4 v = s4[off];
    ushort4 o;
    o.x = f2bf(v.x); o.y = f2bf(v.y); o.z = f2bf(v.z); o.w = f2bf(v.w);
    d4[off] = o;
}

// ---------- GEMM (m97 structure): 128x128 tile, 4 waves, single 32KB LDS buffer ----------
// C[M,NTOT] = A[M,K] * W[NTOT,K]^T, bf16 in, fp32 accum. 256 threads = 2x2 waves,
// each wave a 64x64 output. Simple per-K-tile loop: stage -> sync -> MFMA -> sync;
// stall cover comes from 4 resident blocks/CU (TLP), not intra-block pipelining.
// Chunk-XOR swizzle (0 conflicts), XCD-aware mapping (nt fastest).
// MODE 0: += bias (split col 256), bf16 out via LDS-coalesced epilogue (36KB LDS).
// MODE 1: relu, fp32 direct stores (32KB LDS).
template<int NTOT, int MODE, int NTI>
__global__ __launch_bounds__(256, 4)
void gemm97(const unsigned short* __restrict__ A,
            const unsigned short* __restrict__ W,
            const float* __restrict__ bias0,
            const float* __restrict__ bias1,
            unsigned short* __restrict__ outb,
            float* __restrict__ outf) {
    constexpr int K  = 1024;
    constexpr int NT = 16;                         // K-tiles of 64
    constexpr int LDS_SHORTS = (MODE == 0) ? 18432 : 16384;
    __shared__ unsigned short lds[LDS_SHORTS];     // A[128][64] | B[128][64] (+epilogue room)

    const int t    = threadIdx.x;
    const int wave = t >> 6;
    const int lane = t & 63;

    const int bid = blockIdx.x;
    const int xcd = bid & 7;                       // HW round-robins blocks over 8 XCDs
    const int j   = bid >> 3;
    const int mt  = xcd * 48 + j / NTI;            // 384 M-tiles, 48 per XCD
    const int nt  = j % NTI;                       // nt fastest: A-tile reused NTI times

    const int wr = wave >> 1;                      // 0..1 : rows wr*64..
    const int wc = wave & 1;                       // 0..1 : cols wc*64..

    const size_t aBase = (size_t)mt * 128 * K;
    const size_t bBase = (size_t)nt * 128 * K;

    // staging: 256 thr x 16B = 4KB = 32 rows of 128B per instr; pre-swizzled source
    const int srow = t >> 3;                       // 0..31
    const int scol = ((t & 7) ^ (srow & 7)) << 3;  // element offset
    const unsigned short* gA = A + aBase + (size_t)srow * K + scol;
    const unsigned short* gB = W + bBase + (size_t)srow * K + scol;

    auto STAGE = [&](int tile) {                   // 4 instr A + 4 instr B
#pragma unroll
        for (int i = 0; i < 4; ++i)
            __builtin_amdgcn_global_load_lds(
                (const __attribute__((address_space(1))) void*)(gA + (size_t)(i * 32) * K + tile * 64),
                (__attribute__((address_space(3))) void*)(lds + i * 2048 + wave * 512), 16, 0, 0);
#pragma unroll
        for (int i = 0; i < 4; ++i)
            __builtin_amdgcn_global_load_lds(
                (const __attribute__((address_space(1))) void*)(gB + (size_t)(i * 32) * K + tile * 64),
                (__attribute__((address_space(3))) void*)(lds + 8192 + i * 2048 + wave * 512), 16, 0, 0);
    };

    const int lr  = lane & 15;
    const int lkc = lane >> 4;
    auto LDA = [&](int mi, int kk) -> bf16x8 {
        const int row = wr * 64 + mi * 16 + lr;
        const int ch  = (kk * 4 + lkc) ^ (row & 7);
        return *reinterpret_cast<const bf16x8*>(&lds[row * 64 + ch * 8]);
    };
    auto LDB = [&](int ni, int kk) -> bf16x8 {
        const int row = wc * 64 + ni * 16 + lr;
        const int ch  = (kk * 4 + lkc) ^ (row & 7);
        return *reinterpret_cast<const bf16x8*>(&lds[8192 + row * 64 + ch * 8]);
    };

    f32x4 acc[4][4];
#pragma unroll
    for (int m = 0; m < 4; ++m)
#pragma unroll
        for (int n = 0; n < 4; ++n) acc[m][n] = f32x4{0.f, 0.f, 0.f, 0.f};

    for (int tt = 0; tt < NT; ++tt) {
        STAGE(tt);
        __syncthreads();                           // drains vmcnt(0): tile landed
        bf16x8 af[4][2], bfr[4][2];
#pragma unroll
        for (int m = 0; m < 4; ++m) { af[m][0] = LDA(m, 0); af[m][1] = LDA(m, 1); }
#pragma unroll
        for (int n = 0; n < 4; ++n) { bfr[n][0] = LDB(n, 0); bfr[n][1] = LDB(n, 1); }
#pragma unroll
        for (int m = 0; m < 4; ++m)
#pragma unroll
            for (int n = 0; n < 4; ++n)
#pragma unroll
                for (int kk = 0; kk < 2; ++kk)
                    acc[m][n] = __builtin_amdgcn_mfma_f32_16x16x32_bf16(af[m][kk], bfr[n][kk], acc[m][n], 0, 0, 0);
        __syncthreads();                           // reads done before next stage overwrites
    }

    // -------- epilogue --------
    const int rowOff = (lane >> 4) * 4;            // C/D: col = lane&15, row = rowOff + r
    if (MODE == 1) {
#pragma unroll
        for (int m = 0; m < 4; ++m)
#pragma unroll
            for (int n = 0; n < 4; ++n)
#pragma unroll
                for (int r = 0; r < 4; ++r)
                    outf[(size_t)(mt * 128 + wr * 64 + m * 16 + rowOff + r) * NTOT
                         + nt * 128 + wc * 64 + n * 16 + lr] = fmaxf(acc[m][n][r], 0.f);
    } else {
        unsigned short* lu = lds;                  // 4 regions x 64 x 72 shorts = 18432
#pragma unroll
        for (int mq = 0; mq < 4; ++mq)
#pragma unroll
            for (int n = 0; n < 4; ++n) {
                const int gc = nt * 128 + wc * 64 + n * 16 + lr;
                const float bv = (gc < 256) ? bias0[gc] : bias1[gc - 256];
#pragma unroll
                for (int r = 0; r < 4; ++r)
                    lu[wave * 4608 + (mq * 16 + rowOff + r) * 72 + n * 16 + lr] =
                        f2bf(acc[mq][n][r] + bv);
            }
        __syncthreads();
#pragma unroll
        for (int it = 0; it < 8; ++it) {           // 128 rows x 128 cols bf16
            const int flat = it * 2048 + t * 8;    // shorts
            const int row  = flat >> 7;            // 0..127
            const int col  = flat & 127;
            const int wv   = (row >> 6) * 2 + (col >> 6);
            uint4 v = *reinterpret_cast<const uint4*>(&lu[wv * 4608 + (row & 63) * 72 + (col & 63)]);
            *reinterpret_cast<uint4*>(outb + (size_t)(mt * 128 + row) * NTOT + nt * 128 + col) = v;
        }
    }
}

// ---------- per-batch: sim -> mask -> softmax -> relation + agg (in-place over x_bf16) ----------
// Vectorized LDS access: float4 dot reads, ushort4 agg reads + packed stores.
__global__ __launch_bounds__(256)
void relation_kernel(const unsigned short* __restrict__ TP,   // [M,512] bf16: theta|phi
                     const float* __restrict__ boxes,         // [M,4]
                     unsigned short* __restrict__ xagg,       // [M,1024] bf16 in, agg out (aliased)
                     float* __restrict__ relout) {            // [BT,12,12] fp32
    __shared__ float th[12][260];   // +4 pad
    __shared__ float ph[12][260];
    __shared__ unsigned short xls[12 * 1024];
    __shared__ float cx[12], cy[12];
    __shared__ float sim[12][12];
    __shared__ float rel[12][12];

    const int b = blockIdx.x;
    const int t = threadIdx.x;

    if (t < 12) {
        const float* bx = boxes + ((size_t)b * 12 + t) * 4;
        cx[t] = (bx[0] + bx[2]) * 0.5f;
        cy[t] = (bx[1] + bx[3]) * 0.5f;
    }
    const uint4* tp4 = (const uint4*)(TP + (size_t)b * 6144);
    for (int c = t; c < 768; c += 256) {
        uint4 v = tp4[c];
        const unsigned short* pv = (const unsigned short*)&v;
        const int n = c >> 6;
        const int c0 = (c & 63) << 3;
        if (c0 < 256) {
#pragma unroll
            for (int jj = 0; jj < 8; ++jj) th[n][c0 + jj] = bf2f(pv[jj]);
        } else {
#pragma unroll
            for (int jj = 0; jj < 8; ++jj) ph[n][c0 - 256 + jj] = bf2f(pv[jj]);
        }
    }
    const uint4* x4 = (const uint4*)(xagg + (size_t)b * 12288);
    uint4* xl4 = (uint4*)xls;
    for (int c = t; c < 1536; c += 256) xl4[c] = x4[c];
    __syncthreads();

    if (t < 144) {
        const int n = t / 12, m = t - (t / 12) * 12;
        const float4* tn = (const float4*)&th[n][0];
        const float4* pm = (const float4*)&ph[m][0];
        float a = 0.f;
#pragma unroll 8
        for (int r = 0; r < 64; ++r) {   // same accumulation order as scalar loop
            float4 av = tn[r], bv4 = pm[r];
            a += av.x * bv4.x; a += av.y * bv4.y; a += av.z * bv4.z; a += av.w * bv4.w;
        }
        const float dx = cx[n] - cx[m], dy = cy[n] - cy[m];
        const float d2 = dx * dx + dy * dy;
        const float thr = 31.4f;  // POS_THRESHOLD * OW
        sim[n][m] = (d2 > thr * thr) ? -__builtin_inff() : a * 0.0625f;
    }
    __syncthreads();

    if (t < 12) {
        float mx = -__builtin_inff();
#pragma unroll
        for (int m = 0; m < 12; ++m) mx = fmaxf(mx, sim[t][m]);
        float e[12]; float s = 0.f;
#pragma unroll
        for (int m = 0; m < 12; ++m) { e[m] = expf(sim[t][m] - mx); s += e[m]; }
        const float inv = 1.f / s;
#pragma unroll
        for (int m = 0; m < 12; ++m) {
            const float r = e[m] * inv;
            rel[t][m] = r;
            relout[(size_t)b * 144 + t * 12 + m] = r;
        }
    }
    __syncthreads();

    unsigned short* aggp = xagg + (size_t)b * 12288;
    {
        const int f0 = t * 4;
        float xv[12][4];
#pragma unroll
        for (int m = 0; m < 12; ++m) {
            ushort4 u = *reinterpret_cast<const ushort4*>(&xls[m * 1024 + f0]);
            xv[m][0] = bf2f(u.x); xv[m][1] = bf2f(u.y);
            xv[m][2] = bf2f(u.z); xv[m][3] = bf2f(u.w);
        }
        float rl[12];
#pragma unroll
        for (int n = 0; n < 12; ++n) {
#pragma unroll
            for (int m = 0; m < 12; ++m) rl[m] = rel[n][m];
            ushort4 o;
            float a0 = 0.f, a1 = 0.f, a2 = 0.f, a3 = 0.f;
#pragma unroll
            for (int m = 0; m < 12; ++m) {
                a0 += rl[m] * xv[m][0];
                a1 += rl[m] * xv[m][1];
                a2 += rl[m] * xv[m][2];
                a3 += rl[m] * xv[m][3];
            }
            o.x = f2bf(a0); o.y = f2bf(a1); o.z = f2bf(a2); o.w = f2bf(a3);
            *reinterpret_cast<ushort4*>(&aggp[n * 1024 + f0]) = o;
        }
    }
}

// ---------- launcher ----------
extern "C" void kernel_launch(void* const* d_in, const int* in_sizes, int n_in,
                              void* d_out, int out_size, void* d_ws, size_t ws_size,
                              hipStream_t stream) {
    const float* x     = (const float*)d_in[0];  // [4096,12,1024] fp32
    const float* boxes = (const float*)d_in[1];  // [49152,4]
    const float* Wth   = (const float*)d_in[2];  // [256,1024]
    const float* bth   = (const float*)d_in[3];  // [256]
    const float* Wph   = (const float*)d_in[4];  // [256,1024]
    const float* bph   = (const float*)d_in[5];  // [256]
    const float* Wg    = (const float*)d_in[6];  // [1024,1024]
    float* out = (float*)d_out;                  // 49152*1024 out | 4096*144 relation

    const int M = 49152;
    const size_t XE = (size_t)M * 1024;

    char* ws = (char*)d_ws;
    unsigned short* xb   = (unsigned short*)ws;                 // bf16 x, later agg (in place)
    unsigned short* TP   = (unsigned short*)(ws + 100663296);   // [M,512] bf16 theta|phi
    unsigned short* Wcat = (unsigned short*)(ws + 150994944);   // [512,1024] bf16
    unsigned short* Wgb  = (unsigned short*)(ws + 152043520);   // [1024,1024] bf16

    cast_kernel<<<2048, 256, 0, stream>>>(x, xb, (int)(XE / 4));
    cast3_kernel<<<1536, 256, 0, stream>>>(Wth, Wph, Wg, Wcat, Wcat + 262144, Wgb);

    // gemm0: 384 M-tiles (48/XCD) x NTI=4 -> 1536 blocks, 4 resident/CU
    gemm97<512, 0, 4><<<dim3(1536), 256, 0, stream>>>(xb, Wcat, bth, bph, TP, nullptr);

    relation_kernel<<<4096, 256, 0, stream>>>(TP, boxes, xb, out + XE);

    // gemm1: 384 M-tiles (48/XCD) x NTI=8 -> 3072 blocks, 4 resident/CU
    gemm97<1024, 1, 8><<<dim3(3072), 256, 0, stream>>>(xb, Wgb, nullptr, nullptr, nullptr, out);
}